// Round 6
// baseline (1446.795 us; speedup 1.0000x reference)
//
#include <hip/hip_runtime.h>

#define N_NODES 100000
#define N_EDGES 1600000
#define D 128           // D_IN == D_OUT == 128
#define D4 32           // D in float4 units

#define BNODES 32                              // nodes per bucket
#define NBUCKETS (N_NODES / BNODES)            // 3125 (divides exactly)

// ---- bf16 helpers (bit-level, RNE pack / cheap unpack) ---------------------
__device__ __forceinline__ unsigned short f2bf(float f) {
    unsigned int b = __float_as_uint(f);
    b += 0x7FFFu + ((b >> 16) & 1u);           // round to nearest even
    return (unsigned short)(b >> 16);
}
__device__ __forceinline__ float bf2f(unsigned short u) {
    return __uint_as_float((unsigned int)u << 16);
}

// ---------------------------------------------------------------------------
// Phase 1: support[N, 128] = x @ W, stored as bf16
// ---------------------------------------------------------------------------
__device__ __forceinline__ void fma4(float4& a, float s, const float4& b) {
    a.x = fmaf(s, b.x, a.x);
    a.y = fmaf(s, b.y, a.y);
    a.z = fmaf(s, b.z, a.z);
    a.w = fmaf(s, b.w, a.w);
}

__global__ __launch_bounds__(256) void gemm_xw(
    const float* __restrict__ x, const float* __restrict__ W,
    unsigned short* __restrict__ sup)
{
    __shared__ float4 xs[32 * D4];   // 16 KB
    const int tid = threadIdx.x;
    const int block_row = blockIdx.x * 32;

    const float4* xv = reinterpret_cast<const float4*>(x) + (size_t)block_row * D4;
    #pragma unroll
    for (int i = 0; i < 4; ++i) xs[tid + i * 256] = xv[tid + i * 256];
    __syncthreads();

    const int cg = tid & 31;
    const int rg = tid >> 5;
    const float4* Wv = reinterpret_cast<const float4*>(W);

    float4 acc0 = {0.f, 0.f, 0.f, 0.f};
    float4 acc1 = acc0, acc2 = acc0, acc3 = acc0;

    const int r0 = rg * 4;
    #pragma unroll 8
    for (int k4 = 0; k4 < D4; ++k4) {
        float4 xa = xs[(r0 + 0) * D4 + k4];
        float4 xb = xs[(r0 + 1) * D4 + k4];
        float4 xc = xs[(r0 + 2) * D4 + k4];
        float4 xd = xs[(r0 + 3) * D4 + k4];

        float4 w0 = Wv[(k4 * 4 + 0) * D4 + cg];
        fma4(acc0, xa.x, w0); fma4(acc1, xb.x, w0);
        fma4(acc2, xc.x, w0); fma4(acc3, xd.x, w0);

        float4 w1 = Wv[(k4 * 4 + 1) * D4 + cg];
        fma4(acc0, xa.y, w1); fma4(acc1, xb.y, w1);
        fma4(acc2, xc.y, w1); fma4(acc3, xd.y, w1);

        float4 w2 = Wv[(k4 * 4 + 2) * D4 + cg];
        fma4(acc0, xa.z, w2); fma4(acc1, xb.z, w2);
        fma4(acc2, xc.z, w2); fma4(acc3, xd.z, w2);

        float4 w3 = Wv[(k4 * 4 + 3) * D4 + cg];
        fma4(acc0, xa.w, w3); fma4(acc1, xb.w, w3);
        fma4(acc2, xc.w, w3); fma4(acc3, xd.w, w3);
    }

    // epilogue: pack to bf16, 8 B store per row
    ushort4 p;
    #define STORE_BF16(ACC, R)                                            \
        p.x = f2bf(ACC.x); p.y = f2bf(ACC.y);                             \
        p.z = f2bf(ACC.z); p.w = f2bf(ACC.w);                             \
        *reinterpret_cast<ushort4*>(sup + (size_t)(block_row + r0 + R) * D + cg * 4) = p;
    STORE_BF16(acc0, 0)
    STORE_BF16(acc1, 1)
    STORE_BF16(acc2, 2)
    STORE_BF16(acc3, 3)
    #undef STORE_BF16
}

// ---------------------------------------------------------------------------
// Coarse bucket build: histogram(3125) -> single-block scan -> fill pairs
// pair.x = col | (row_local << 20), pair.y = weight bits
// ---------------------------------------------------------------------------
__global__ __launch_bounds__(256) void hist_buckets(
    const int* __restrict__ row, int* __restrict__ cnt)
{
    int e = blockIdx.x * 256 + threadIdx.x;
    if (e < N_EDGES) atomicAdd(&cnt[row[e] >> 5], 1);
}

__global__ __launch_bounds__(1024) void scan_buckets(
    const int* __restrict__ cnt, int* __restrict__ boff, int* __restrict__ cur)
{
    __shared__ int buf[1024];
    const int tid = threadIdx.x;
    int v[4];
    int s = 0;
    #pragma unroll
    for (int j = 0; j < 4; ++j) {
        int i = tid * 4 + j;
        v[j] = (i < NBUCKETS) ? cnt[i] : 0;
        s += v[j];
    }
    buf[tid] = s;
    __syncthreads();
    #pragma unroll
    for (int off = 1; off < 1024; off <<= 1) {
        int add = (tid >= off) ? buf[tid - off] : 0;
        __syncthreads();
        buf[tid] += add;
        __syncthreads();
    }
    int excl = buf[tid] - s;
    #pragma unroll
    for (int j = 0; j < 4; ++j) {
        int i = tid * 4 + j;
        if (i < NBUCKETS) { boff[i] = excl; cur[i] = excl; excl += v[j]; }
    }
    if (tid == 0) boff[NBUCKETS] = N_EDGES;
}

__global__ __launch_bounds__(256) void fill_coarse(
    const int* __restrict__ row, const int* __restrict__ col,
    const float* __restrict__ ew, int* __restrict__ cur,
    int2* __restrict__ pairs)
{
    int e = blockIdx.x * 256 + threadIdx.x;
    if (e >= N_EDGES) return;
    int r = row[e];
    int pos = atomicAdd(&cur[r >> 5], 1);
    pairs[pos] = make_int2(col[e] | ((r & 31) << 20), __float_as_int(ew[e]));
}

// ---------------------------------------------------------------------------
// Gather: one block per bucket of 32 nodes. 32x128 fp32 accumulator in LDS.
// Wave processes one edge: uniform pair load, bf16 support row read
// (lane -> elements l and l+64: stride-1, conflict-free LDS), LDS atomicAdd.
// One coalesced 16 KB out write per block. No global fp32 atomics.
// ---------------------------------------------------------------------------
__global__ __launch_bounds__(256) void gather_lds(
    const int* __restrict__ boff, const int2* __restrict__ pairs,
    const unsigned short* __restrict__ sup, float* __restrict__ out)
{
    __shared__ float acc[BNODES * D];          // 16 KB
    const int b = blockIdx.x;
    const int tid = threadIdx.x;

    float4* accv = reinterpret_cast<float4*>(acc);
    #pragma unroll
    for (int i = 0; i < 4; ++i)
        accv[tid + i * 256] = make_float4(0.f, 0.f, 0.f, 0.f);
    __syncthreads();

    const int beg = boff[b];
    const int end = boff[b + 1];
    const int wv = tid >> 6;
    const int lane = tid & 63;

    int e = beg + wv;
    // 2-edge unroll: two independent pair->support load chains in flight
    for (; e + 4 < end; e += 8) {
        int2 pa = pairs[e];
        int2 pb = pairs[e + 4];
        const unsigned short* sa = sup + (size_t)(pa.x & 0xFFFFF) * D;
        const unsigned short* sb = sup + (size_t)(pb.x & 0xFFFFF) * D;
        float a0 = bf2f(sa[lane]), a1 = bf2f(sa[lane + 64]);
        float b0 = bf2f(sb[lane]), b1 = bf2f(sb[lane + 64]);
        float wa = __int_as_float(pa.y);
        float wb = __int_as_float(pb.y);
        int la = (pa.x >> 20) * D;
        int lb = (pb.x >> 20) * D;
        atomicAdd(&acc[la + lane],      wa * a0);
        atomicAdd(&acc[la + lane + 64], wa * a1);
        atomicAdd(&acc[lb + lane],      wb * b0);
        atomicAdd(&acc[lb + lane + 64], wb * b1);
    }
    if (e < end) {
        int2 p = pairs[e];
        const unsigned short* sr = sup + (size_t)(p.x & 0xFFFFF) * D;
        float s0 = bf2f(sr[lane]), s1 = bf2f(sr[lane + 64]);
        float w = __int_as_float(p.y);
        int l = (p.x >> 20) * D;
        atomicAdd(&acc[l + lane],      w * s0);
        atomicAdd(&acc[l + lane + 64], w * s1);
    }
    __syncthreads();

    float4* o4 = reinterpret_cast<float4*>(out + (size_t)b * BNODES * D);
    #pragma unroll
    for (int i = 0; i < 4; ++i)
        o4[tid + i * 256] = accv[tid + i * 256];
}

// ---------------------------------------------------------------------------
// Fallback (ws too small): atomic scatter reading bf16 support.
// ---------------------------------------------------------------------------
__global__ __launch_bounds__(256) void scatter_edges(
    const int* __restrict__ row, const int* __restrict__ col,
    const float* __restrict__ ew, const unsigned short* __restrict__ sup,
    float* __restrict__ out)
{
    const int e = blockIdx.x * 4 + (threadIdx.x >> 6);
    if (e >= N_EDGES) return;
    const int lane = threadIdx.x & 63;

    const int r = row[e];
    const int c = col[e];
    const float w = ew[e];
    const unsigned short* sr = sup + (size_t)c * D;
    float s0 = bf2f(sr[lane]), s1 = bf2f(sr[lane + 64]);
    atomicAdd(out + (size_t)r * D + lane,      w * s0);
    atomicAdd(out + (size_t)r * D + lane + 64, w * s1);
}

extern "C" void kernel_launch(void* const* d_in, const int* in_sizes, int n_in,
                              void* d_out, int out_size, void* d_ws, size_t ws_size,
                              hipStream_t stream)
{
    const float* x      = (const float*)d_in[0];   // [N_NODES, 128]
    const int*   row    = (const int*)d_in[1];     // [N_EDGES]
    const int*   col    = (const int*)d_in[2];     // [N_EDGES]
    const float* ew     = (const float*)d_in[3];   // [N_EDGES]
    const float* weight = (const float*)d_in[4];   // [128, 128]
    float* out = (float*)d_out;                    // [N_NODES, 128]

    char* ws = (char*)d_ws;
    const size_t off_sup   = 0;                                        // 25.6 MB
    const size_t off_pairs = off_sup + (size_t)N_NODES * D * 2;        // 12.8 MB
    const size_t off_cnt   = off_pairs + (size_t)N_EDGES * 8;          // 12.5 KB
    const size_t off_boff  = off_cnt + (size_t)NBUCKETS * 4;
    const size_t off_cur   = off_boff + (size_t)(NBUCKETS + 1) * 4;
    const size_t required  = off_cur + (size_t)NBUCKETS * 4;

    unsigned short* sup = (unsigned short*)(ws + off_sup);

    if (ws_size >= required) {
        int2* pairs = (int2*)(ws + off_pairs);
        int*  cnt   = (int*)(ws + off_cnt);
        int*  boff  = (int*)(ws + off_boff);
        int*  cur   = (int*)(ws + off_cur);

        // --- coarse bucket build ---
        hipMemsetAsync(cnt, 0, (size_t)NBUCKETS * 4, stream);
        hist_buckets<<<(N_EDGES + 255) / 256, 256, 0, stream>>>(row, cnt);
        scan_buckets<<<1, 1024, 0, stream>>>(cnt, boff, cur);
        fill_coarse<<<(N_EDGES + 255) / 256, 256, 0, stream>>>(row, col, ew, cur, pairs);

        // --- GEMM last before gather: keeps support hot in L2/L3 ---
        gemm_xw<<<N_NODES / 32, 256, 0, stream>>>(x, weight, sup);

        // --- gather: one block per bucket, writes every output row ---
        gather_lds<<<NBUCKETS, 256, 0, stream>>>(boff, pairs, sup, out);
    } else {
        gemm_xw<<<N_NODES / 32, 256, 0, stream>>>(x, weight, sup);
        hipMemsetAsync(d_out, 0, (size_t)N_NODES * D * sizeof(float), stream);
        scatter_edges<<<(N_EDGES + 3) / 4, 256, 0, stream>>>(row, col, ew, sup, out);
    }
}

// Round 7
// 337.692 us; speedup vs baseline: 4.2844x; 4.2844x over previous
//
#include <hip/hip_runtime.h>

#define N_NODES 100000
#define N_EDGES 1600000
#define D 128           // D_IN == D_OUT == 128
#define D4 32           // D in float4 units

// ---------------------------------------------------------------------------
// Phase 1: support[N, 128] = x[N, 128] @ W[128, 128]   (fp32, vector ALU)
// ---------------------------------------------------------------------------
__device__ __forceinline__ void fma4(float4& a, float s, const float4& b) {
    a.x = fmaf(s, b.x, a.x);
    a.y = fmaf(s, b.y, a.y);
    a.z = fmaf(s, b.z, a.z);
    a.w = fmaf(s, b.w, a.w);
}

__global__ __launch_bounds__(256) void gemm_xw(
    const float* __restrict__ x, const float* __restrict__ W,
    float* __restrict__ support)
{
    __shared__ float4 xs[32 * D4];   // 16 KB
    const int tid = threadIdx.x;
    const int block_row = blockIdx.x * 32;

    const float4* xv = reinterpret_cast<const float4*>(x) + (size_t)block_row * D4;
    #pragma unroll
    for (int i = 0; i < 4; ++i) xs[tid + i * 256] = xv[tid + i * 256];
    __syncthreads();

    const int cg = tid & 31;         // column group (4 cols)
    const int rg = tid >> 5;         // row group (4 rows)
    const float4* Wv = reinterpret_cast<const float4*>(W);

    float4 acc0 = {0.f, 0.f, 0.f, 0.f};
    float4 acc1 = acc0, acc2 = acc0, acc3 = acc0;

    const int r0 = rg * 4;
    #pragma unroll 8
    for (int k4 = 0; k4 < D4; ++k4) {
        float4 xa = xs[(r0 + 0) * D4 + k4];
        float4 xb = xs[(r0 + 1) * D4 + k4];
        float4 xc = xs[(r0 + 2) * D4 + k4];
        float4 xd = xs[(r0 + 3) * D4 + k4];

        float4 w0 = Wv[(k4 * 4 + 0) * D4 + cg];
        fma4(acc0, xa.x, w0); fma4(acc1, xb.x, w0);
        fma4(acc2, xc.x, w0); fma4(acc3, xd.x, w0);

        float4 w1 = Wv[(k4 * 4 + 1) * D4 + cg];
        fma4(acc0, xa.y, w1); fma4(acc1, xb.y, w1);
        fma4(acc2, xc.y, w1); fma4(acc3, xd.y, w1);

        float4 w2 = Wv[(k4 * 4 + 2) * D4 + cg];
        fma4(acc0, xa.z, w2); fma4(acc1, xb.z, w2);
        fma4(acc2, xc.z, w2); fma4(acc3, xd.z, w2);

        float4 w3 = Wv[(k4 * 4 + 3) * D4 + cg];
        fma4(acc0, xa.w, w3); fma4(acc1, xb.w, w3);
        fma4(acc2, xc.w, w3); fma4(acc3, xd.w, w3);
    }

    float4* sv = reinterpret_cast<float4*>(support);
    sv[(size_t)(block_row + r0 + 0) * D4 + cg] = acc0;
    sv[(size_t)(block_row + r0 + 1) * D4 + cg] = acc1;
    sv[(size_t)(block_row + r0 + 2) * D4 + cg] = acc2;
    sv[(size_t)(block_row + r0 + 3) * D4 + cg] = acc3;
}

// ---------------------------------------------------------------------------
// Linked-list build: next[e] = old head of row[e]. No (col,w) copy, no scan,
// no permutation. Writes: next 6.4 MB sequential + head 400 KB scattered.
// ---------------------------------------------------------------------------
__global__ __launch_bounds__(256) void build_list(
    const int* __restrict__ row, int* __restrict__ head, int* __restrict__ next)
{
    int e = blockIdx.x * 256 + threadIdx.x;
    if (e < N_EDGES) next[e] = atomicExch(&head[row[e]], e);
}

// ---------------------------------------------------------------------------
// Gather: half-wave (32 lanes, float4 = full 128-col row) per node chases the
// node's edge list. Serial dependency per hop is only next[e]; col/ew/support
// loads overlap. 2 independent chases per wave. One 512 B store per node.
// ---------------------------------------------------------------------------
__global__ __launch_bounds__(256) void gather_list(
    const int* __restrict__ head, const int* __restrict__ next,
    const int* __restrict__ col, const float* __restrict__ ew,
    const float* __restrict__ support, float* __restrict__ out)
{
    const int half = threadIdx.x >> 5;          // 0..7
    const int lane = threadIdx.x & 31;
    const int node = blockIdx.x * 8 + half;     // grid exact: 12500*8 = N_NODES

    const float4* sv = reinterpret_cast<const float4*>(support);
    float4 acc = {0.f, 0.f, 0.f, 0.f};

    int e = head[node];
    while (e >= 0) {
        int   nx = next[e];                     // issue chase first (critical path)
        int   c  = col[e];
        float w  = ew[e];
        float4 s = sv[(size_t)c * D4 + lane];
        acc.x = fmaf(w, s.x, acc.x);
        acc.y = fmaf(w, s.y, acc.y);
        acc.z = fmaf(w, s.z, acc.z);
        acc.w = fmaf(w, s.w, acc.w);
        e = nx;
    }
    reinterpret_cast<float4*>(out)[(size_t)node * D4 + lane] = acc;
}

// ---------------------------------------------------------------------------
// Fallback (ws too small): atomic scatter, proven correct in R3.
// ---------------------------------------------------------------------------
__global__ __launch_bounds__(256) void scatter_edges(
    const int* __restrict__ row, const int* __restrict__ col,
    const float* __restrict__ ew, const float* __restrict__ support,
    float* __restrict__ out)
{
    const int e = blockIdx.x * 8 + (threadIdx.x >> 5);
    if (e >= N_EDGES) return;
    const int lane = threadIdx.x & 31;

    const int r = row[e];
    const int c = col[e];
    const float w = ew[e];

    float4 s = reinterpret_cast<const float4*>(support)[(size_t)c * D4 + lane];
    float* o = out + (size_t)r * D + lane * 4;
    atomicAdd(o + 0, w * s.x);
    atomicAdd(o + 1, w * s.y);
    atomicAdd(o + 2, w * s.z);
    atomicAdd(o + 3, w * s.w);
}

extern "C" void kernel_launch(void* const* d_in, const int* in_sizes, int n_in,
                              void* d_out, int out_size, void* d_ws, size_t ws_size,
                              hipStream_t stream)
{
    const float* x      = (const float*)d_in[0];   // [N_NODES, 128]
    const int*   row    = (const int*)d_in[1];     // [N_EDGES]
    const int*   col    = (const int*)d_in[2];     // [N_EDGES]
    const float* ew     = (const float*)d_in[3];   // [N_EDGES]
    const float* weight = (const float*)d_in[4];   // [128, 128]
    float* out = (float*)d_out;                    // [N_NODES, 128]

    char* ws = (char*)d_ws;
    const size_t off_support = 0;                                      // 51.2 MB
    const size_t off_head    = off_support + (size_t)N_NODES * D * 4;  // 400 KB
    const size_t off_next    = off_head + (size_t)N_NODES * 4;         // 6.4 MB
    const size_t required    = off_next + (size_t)N_EDGES * 4;

    float* support = (float*)(ws + off_support);

    if (ws_size >= required) {
        int* head = (int*)(ws + off_head);
        int* next = (int*)(ws + off_next);

        // --- list build (independent of GEMM) ---
        hipMemsetAsync(head, 0xFF, (size_t)N_NODES * 4, stream);       // head = -1
        build_list<<<(N_EDGES + 255) / 256, 256, 0, stream>>>(row, head, next);

        // --- GEMM last before gather: keeps support hot in L2/L3 ---
        gemm_xw<<<N_NODES / 32, 256, 0, stream>>>(x, weight, support);

        // --- gather: writes every output row (no out memset needed) ---
        gather_list<<<N_NODES / 8, 256, 0, stream>>>(head, next, col, ew, support, out);
    } else {
        // Fallback: atomic scatter path (R3)
        gemm_xw<<<N_NODES / 32, 256, 0, stream>>>(x, weight, support);
        hipMemsetAsync(d_out, 0, (size_t)N_NODES * D * sizeof(float), stream);
        scatter_edges<<<N_EDGES / 8, 256, 0, stream>>>(row, col, ew, support, out);
    }
}

// Round 8
// 270.484 us; speedup vs baseline: 5.3489x; 1.2485x over previous
//
#include <hip/hip_runtime.h>

#define N_NODES 100000
#define N_EDGES 1600000
#define D 128           // D_IN == D_OUT == 128
#define D4 32           // D in float4 units

// ---- bf16 helpers (bit-level, RNE pack / cheap unpack) ---------------------
__device__ __forceinline__ unsigned short f2bf(float f) {
    unsigned int b = __float_as_uint(f);
    b += 0x7FFFu + ((b >> 16) & 1u);           // round to nearest even
    return (unsigned short)(b >> 16);
}
__device__ __forceinline__ float bf2f(unsigned short u) {
    return __uint_as_float((unsigned int)u << 16);
}

// ---------------------------------------------------------------------------
// Phase 1: support[N, 128] = x @ W (fp32 compute, bf16 store)
// ---------------------------------------------------------------------------
__device__ __forceinline__ void fma4(float4& a, float s, const float4& b) {
    a.x = fmaf(s, b.x, a.x);
    a.y = fmaf(s, b.y, a.y);
    a.z = fmaf(s, b.z, a.z);
    a.w = fmaf(s, b.w, a.w);
}

__global__ __launch_bounds__(256) void gemm_xw(
    const float* __restrict__ x, const float* __restrict__ W,
    unsigned short* __restrict__ sup)
{
    __shared__ float4 xs[32 * D4];   // 16 KB
    const int tid = threadIdx.x;
    const int block_row = blockIdx.x * 32;

    const float4* xv = reinterpret_cast<const float4*>(x) + (size_t)block_row * D4;
    #pragma unroll
    for (int i = 0; i < 4; ++i) xs[tid + i * 256] = xv[tid + i * 256];
    __syncthreads();

    const int cg = tid & 31;         // column group (4 cols)
    const int rg = tid >> 5;         // row group (4 rows)
    const float4* Wv = reinterpret_cast<const float4*>(W);

    float4 acc0 = {0.f, 0.f, 0.f, 0.f};
    float4 acc1 = acc0, acc2 = acc0, acc3 = acc0;

    const int r0 = rg * 4;
    #pragma unroll 8
    for (int k4 = 0; k4 < D4; ++k4) {
        float4 xa = xs[(r0 + 0) * D4 + k4];
        float4 xb = xs[(r0 + 1) * D4 + k4];
        float4 xc = xs[(r0 + 2) * D4 + k4];
        float4 xd = xs[(r0 + 3) * D4 + k4];

        float4 w0 = Wv[(k4 * 4 + 0) * D4 + cg];
        fma4(acc0, xa.x, w0); fma4(acc1, xb.x, w0);
        fma4(acc2, xc.x, w0); fma4(acc3, xd.x, w0);

        float4 w1 = Wv[(k4 * 4 + 1) * D4 + cg];
        fma4(acc0, xa.y, w1); fma4(acc1, xb.y, w1);
        fma4(acc2, xc.y, w1); fma4(acc3, xd.y, w1);

        float4 w2 = Wv[(k4 * 4 + 2) * D4 + cg];
        fma4(acc0, xa.z, w2); fma4(acc1, xb.z, w2);
        fma4(acc2, xc.z, w2); fma4(acc3, xd.z, w2);

        float4 w3 = Wv[(k4 * 4 + 3) * D4 + cg];
        fma4(acc0, xa.w, w3); fma4(acc1, xb.w, w3);
        fma4(acc2, xc.w, w3); fma4(acc3, xd.w, w3);
    }

    // epilogue: pack to bf16, 8 B store per row per thread
    ushort4 p;
    #define STORE_BF16(ACC, R)                                            \
        p.x = f2bf(ACC.x); p.y = f2bf(ACC.y);                             \
        p.z = f2bf(ACC.z); p.w = f2bf(ACC.w);                             \
        *reinterpret_cast<ushort4*>(sup + (size_t)(block_row + r0 + R) * D + cg * 4) = p;
    STORE_BF16(acc0, 0)
    STORE_BF16(acc1, 1)
    STORE_BF16(acc2, 2)
    STORE_BF16(acc3, 3)
    #undef STORE_BF16
}

// ---------------------------------------------------------------------------
// Linked-list build with packed edge records:
//   entries[e] = {next, col, ew_bits, 0}   (int4, sequential 16 B writes)
// One random line-fetch per edge in the gather instead of three.
// ---------------------------------------------------------------------------
__global__ __launch_bounds__(256) void build_list(
    const int* __restrict__ row, const int* __restrict__ col,
    const float* __restrict__ ew,
    int* __restrict__ head, int4* __restrict__ entries)
{
    int e = blockIdx.x * 256 + threadIdx.x;
    if (e >= N_EDGES) return;
    int nx = atomicExch(&head[row[e]], e);
    entries[e] = make_int4(nx, col[e], __float_as_int(ew[e]), 0);
}

// ---------------------------------------------------------------------------
// Gather: half-wave (32 lanes) per node chases the list. Per edge: one int4
// entry fetch (broadcast) + bf16 support row (32 x ushort4 = 256 B coalesced).
// fp32 accumulate, one 512 B store per node.
// ---------------------------------------------------------------------------
__global__ __launch_bounds__(256) void gather_list(
    const int* __restrict__ head, const int4* __restrict__ entries,
    const unsigned short* __restrict__ sup, float* __restrict__ out)
{
    const int half = threadIdx.x >> 5;          // 0..7
    const int lane = threadIdx.x & 31;
    const int node = blockIdx.x * 8 + half;     // grid exact: 12500*8 = N_NODES

    float4 acc = {0.f, 0.f, 0.f, 0.f};

    int e = head[node];
    while (e >= 0) {
        int4 en = entries[e];                   // next, col, w_bits (one line)
        float w = __int_as_float(en.z);
        ushort4 s = reinterpret_cast<const ushort4*>(sup + (size_t)en.y * D)[lane];
        acc.x = fmaf(w, bf2f(s.x), acc.x);
        acc.y = fmaf(w, bf2f(s.y), acc.y);
        acc.z = fmaf(w, bf2f(s.z), acc.z);
        acc.w = fmaf(w, bf2f(s.w), acc.w);
        e = en.x;
    }
    reinterpret_cast<float4*>(out)[(size_t)node * D4 + lane] = acc;
}

// ---------------------------------------------------------------------------
// Fallback (ws too small): atomic scatter reading bf16 support.
// ---------------------------------------------------------------------------
__global__ __launch_bounds__(256) void scatter_edges(
    const int* __restrict__ row, const int* __restrict__ col,
    const float* __restrict__ ew, const unsigned short* __restrict__ sup,
    float* __restrict__ out)
{
    const int e = blockIdx.x * 8 + (threadIdx.x >> 5);
    if (e >= N_EDGES) return;
    const int lane = threadIdx.x & 31;

    const int r = row[e];
    const int c = col[e];
    const float w = ew[e];
    ushort4 s = reinterpret_cast<const ushort4*>(sup + (size_t)c * D)[lane];
    float* o = out + (size_t)r * D + lane * 4;
    atomicAdd(o + 0, w * bf2f(s.x));
    atomicAdd(o + 1, w * bf2f(s.y));
    atomicAdd(o + 2, w * bf2f(s.z));
    atomicAdd(o + 3, w * bf2f(s.w));
}

extern "C" void kernel_launch(void* const* d_in, const int* in_sizes, int n_in,
                              void* d_out, int out_size, void* d_ws, size_t ws_size,
                              hipStream_t stream)
{
    const float* x      = (const float*)d_in[0];   // [N_NODES, 128]
    const int*   row    = (const int*)d_in[1];     // [N_EDGES]
    const int*   col    = (const int*)d_in[2];     // [N_EDGES]
    const float* ew     = (const float*)d_in[3];   // [N_EDGES]
    const float* weight = (const float*)d_in[4];   // [128, 128]
    float* out = (float*)d_out;                    // [N_NODES, 128]

    char* ws = (char*)d_ws;
    const size_t off_sup     = 0;                                      // 25.6 MB
    const size_t off_head    = off_sup + (size_t)N_NODES * D * 2;      // 400 KB
    const size_t off_entries = off_head + (((size_t)N_NODES * 4 + 15) & ~(size_t)15);
    const size_t required    = off_entries + (size_t)N_EDGES * 16;     // 25.6 MB

    unsigned short* sup = (unsigned short*)(ws + off_sup);

    if (ws_size >= required) {
        int*  head    = (int*)(ws + off_head);
        int4* entries = (int4*)(ws + off_entries);

        // --- list build (independent of GEMM) ---
        hipMemsetAsync(head, 0xFF, (size_t)N_NODES * 4, stream);       // head = -1
        build_list<<<(N_EDGES + 255) / 256, 256, 0, stream>>>(row, col, ew, head, entries);

        // --- GEMM last before gather: keeps support hot in L2/L3 ---
        gemm_xw<<<N_NODES / 32, 256, 0, stream>>>(x, weight, sup);

        // --- gather: writes every output row (no out memset needed) ---
        gather_list<<<N_NODES / 8, 256, 0, stream>>>(head, entries, sup, out);
    } else {
        gemm_xw<<<N_NODES / 32, 256, 0, stream>>>(x, weight, sup);
        hipMemsetAsync(d_out, 0, (size_t)N_NODES * D * sizeof(float), stream);
        scatter_edges<<<N_EDGES / 8, 256, 0, stream>>>(row, col, ew, sup, out);
    }
}

// Round 9
// 201.892 us; speedup vs baseline: 7.1662x; 1.3397x over previous
//
#include <hip/hip_runtime.h>

#define N_NODES 100000
#define N_EDGES 1600000
#define D 128           // D_IN == D_OUT == 128
#define D4 32           // D in float4 units

#define BM 128                                   // gemm rows per block
#define GEMM_BLOCKS ((N_NODES + BM - 1) / BM)    // 782 (tail block: 32 rows)
#define LDK 136                                  // padded LDS row (bf16 elems): +16 B kills bank conflicts

typedef __attribute__((ext_vector_type(8))) short short8;   // 8 bf16 = 4 VGPRs (MFMA A/B frag)
typedef __attribute__((ext_vector_type(4))) float floatx4;  // MFMA C/D frag

// ---- bf16 helpers (bit-level, RNE pack / cheap unpack) ---------------------
__device__ __forceinline__ unsigned short f2bf(float f) {
    unsigned int b = __float_as_uint(f);
    b += 0x7FFFu + ((b >> 16) & 1u);           // round to nearest even
    return (unsigned short)(b >> 16);
}
__device__ __forceinline__ float bf2f(unsigned short u) {
    return __uint_as_float((unsigned int)u << 16);
}

// ---------------------------------------------------------------------------
// W^T prep (once): wt[n*128+k] = bf16(W[k*128+n]). 32 KB output, trivial.
// ---------------------------------------------------------------------------
__global__ __launch_bounds__(256) void w_prep(
    const float* __restrict__ W, unsigned short* __restrict__ wt)
{
    int idx = blockIdx.x * 256 + threadIdx.x;   // 0..16383
    int k = idx >> 7, n = idx & 127;
    wt[(size_t)n * D + k] = f2bf(W[idx]);
}

// ---------------------------------------------------------------------------
// Fused: support = bf16(x) @ bf16(W) via MFMA  +  edge linked-list build.
// Block: 256 threads (4 waves), BM=128 rows, full N=K=128.
// Wave w owns rows [w*32, w*32+32): 2 (M) x 8 (N) fragment tiles, 4 K-steps.
// Build section grid-strides the edge array; overlaps other waves' MFMA work.
// ---------------------------------------------------------------------------
__global__ __launch_bounds__(256) void gemm_build(
    const float* __restrict__ x, const unsigned short* __restrict__ wt,
    unsigned short* __restrict__ sup,
    const int* __restrict__ row, const int* __restrict__ col,
    const float* __restrict__ ew,
    int* __restrict__ head, int4* __restrict__ entries)
{
    __shared__ unsigned short xs[BM * LDK];      // 34.0 KB
    __shared__ unsigned short wl[D * LDK];       // 34.0 KB

    const int tid = threadIdx.x;
    const int brow = blockIdx.x * BM;

    // stage W^T (row-major [n][k]) -> LDS, 16 B vector loads, padded rows
    {
        const short8* wv = reinterpret_cast<const short8*>(wt);
        #pragma unroll
        for (int i = 0; i < 8; ++i) {
            int idx = tid + i * 256;             // short8 index, 2048 total
            int n = idx >> 4, k8 = idx & 15;
            *reinterpret_cast<short8*>(&wl[n * LDK + k8 * 8]) = wv[idx];
        }
    }
    // stage x tile (fp32 -> bf16), 128 rows x 32 float4, zero-pad tail rows
    {
        const float4* xv = reinterpret_cast<const float4*>(x);
        #pragma unroll
        for (int i = 0; i < 16; ++i) {
            int idx = tid + i * 256;             // 0..4095
            int r = idx >> 5, k4 = idx & 31;
            int gr = brow + r;
            float4 v = (gr < N_NODES) ? xv[(size_t)gr * D4 + k4]
                                      : make_float4(0.f, 0.f, 0.f, 0.f);
            ushort4 p;
            p.x = f2bf(v.x); p.y = f2bf(v.y); p.z = f2bf(v.z); p.w = f2bf(v.w);
            *reinterpret_cast<ushort4*>(&xs[r * LDK + k4 * 4]) = p;
        }
    }
    __syncthreads();

    const int wave = tid >> 6;
    const int lane = tid & 63;
    const int l15  = lane & 15;
    const int lk8  = (lane >> 4) * 8;            // per-lane K sub-offset

    floatx4 acc[2][8];
    #pragma unroll
    for (int m = 0; m < 2; ++m)
        #pragma unroll
        for (int n = 0; n < 8; ++n) acc[m][n] = (floatx4){0.f, 0.f, 0.f, 0.f};

    const int wrow = wave * 32;
    #pragma unroll
    for (int kk = 0; kk < 4; ++kk) {
        int kb = kk * 32 + lk8;
        // A frags: row = lane&15 (+16 for m=1), k = kb..kb+7 (contiguous 16 B)
        short8 a0 = *reinterpret_cast<const short8*>(&xs[(wrow + l15) * LDK + kb]);
        short8 a1 = *reinterpret_cast<const short8*>(&xs[(wrow + 16 + l15) * LDK + kb]);
        #pragma unroll
        for (int n = 0; n < 8; ++n) {
            // B frag: col = n*16 + (lane&15), k = kb..kb+7 (W^T row-major)
            short8 b = *reinterpret_cast<const short8*>(&wl[(n * 16 + l15) * LDK + kb]);
            acc[0][n] = __builtin_amdgcn_mfma_f32_16x16x32_bf16(a0, b, acc[0][n], 0, 0, 0);
            acc[1][n] = __builtin_amdgcn_mfma_f32_16x16x32_bf16(a1, b, acc[1][n], 0, 0, 0);
        }
    }

    // epilogue: D col = lane&15, row = (lane>>4)*4 + r  (m89-verified)
    const int rbase = brow + wrow + (lane >> 4) * 4;
    #pragma unroll
    for (int m = 0; m < 2; ++m) {
        #pragma unroll
        for (int r = 0; r < 4; ++r) {
            int grow = rbase + m * 16 + r;
            if (grow < N_NODES) {
                #pragma unroll
                for (int n = 0; n < 8; ++n)
                    sup[(size_t)grow * D + n * 16 + l15] = f2bf(acc[m][n][r]);
            }
        }
    }

    // fused edge-list build (grid-stride over edges; no sync needed — next
    // kernel boundary orders it before gather)
    for (int e = blockIdx.x * 256 + tid; e < N_EDGES; e += GEMM_BLOCKS * 256) {
        int nx = atomicExch(&head[row[e]], e);
        entries[e] = make_int4(nx, col[e], __float_as_int(ew[e]), 0);
    }
}

// ---------------------------------------------------------------------------
// Gather: half-wave (32 lanes) per node chases the list. Per edge: one int4
// entry fetch (broadcast) + bf16 support row (32 x ushort4 = 256 B coalesced).
// ---------------------------------------------------------------------------
__global__ __launch_bounds__(256) void gather_list(
    const int* __restrict__ head, const int4* __restrict__ entries,
    const unsigned short* __restrict__ sup, float* __restrict__ out)
{
    const int half = threadIdx.x >> 5;          // 0..7
    const int lane = threadIdx.x & 31;
    const int node = blockIdx.x * 8 + half;     // grid exact: 12500*8 = N_NODES

    float4 acc = {0.f, 0.f, 0.f, 0.f};

    int e = head[node];
    while (e >= 0) {
        int4 en = entries[e];                   // next, col, w_bits (one line)
        float w = __int_as_float(en.z);
        ushort4 s = reinterpret_cast<const ushort4*>(sup + (size_t)en.y * D)[lane];
        acc.x = fmaf(w, bf2f(s.x), acc.x);
        acc.y = fmaf(w, bf2f(s.y), acc.y);
        acc.z = fmaf(w, bf2f(s.z), acc.z);
        acc.w = fmaf(w, bf2f(s.w), acc.w);
        e = en.x;
    }
    reinterpret_cast<float4*>(out)[(size_t)node * D4 + lane] = acc;
}

// ---------------------------------------------------------------------------
// Fallback path (ws too small): VALU gemm + atomic scatter (proven R3/R8).
// ---------------------------------------------------------------------------
__device__ __forceinline__ void fma4(float4& a, float s, const float4& b) {
    a.x = fmaf(s, b.x, a.x);
    a.y = fmaf(s, b.y, a.y);
    a.z = fmaf(s, b.z, a.z);
    a.w = fmaf(s, b.w, a.w);
}

__global__ __launch_bounds__(256) void gemm_xw(
    const float* __restrict__ x, const float* __restrict__ W,
    unsigned short* __restrict__ sup)
{
    __shared__ float4 xs[32 * D4];
    const int tid = threadIdx.x;
    const int block_row = blockIdx.x * 32;

    const float4* xv = reinterpret_cast<const float4*>(x) + (size_t)block_row * D4;
    #pragma unroll
    for (int i = 0; i < 4; ++i) xs[tid + i * 256] = xv[tid + i * 256];
    __syncthreads();

    const int cg = tid & 31;
    const int rg = tid >> 5;
    const float4* Wv = reinterpret_cast<const float4*>(W);

    float4 acc0 = {0.f, 0.f, 0.f, 0.f};
    float4 acc1 = acc0, acc2 = acc0, acc3 = acc0;

    const int r0 = rg * 4;
    #pragma unroll 8
    for (int k4 = 0; k4 < D4; ++k4) {
        float4 xa = xs[(r0 + 0) * D4 + k4];
        float4 xb = xs[(r0 + 1) * D4 + k4];
        float4 xc = xs[(r0 + 2) * D4 + k4];
        float4 xd = xs[(r0 + 3) * D4 + k4];
        float4 w0 = Wv[(k4 * 4 + 0) * D4 + cg];
        fma4(acc0, xa.x, w0); fma4(acc1, xb.x, w0);
        fma4(acc2, xc.x, w0); fma4(acc3, xd.x, w0);
        float4 w1 = Wv[(k4 * 4 + 1) * D4 + cg];
        fma4(acc0, xa.y, w1); fma4(acc1, xb.y, w1);
        fma4(acc2, xc.y, w1); fma4(acc3, xd.y, w1);
        float4 w2 = Wv[(k4 * 4 + 2) * D4 + cg];
        fma4(acc0, xa.z, w2); fma4(acc1, xb.z, w2);
        fma4(acc2, xc.z, w2); fma4(acc3, xd.z, w2);
        float4 w3 = Wv[(k4 * 4 + 3) * D4 + cg];
        fma4(acc0, xa.w, w3); fma4(acc1, xb.w, w3);
        fma4(acc2, xc.w, w3); fma4(acc3, xd.w, w3);
    }

    ushort4 p;
    #define STORE_BF16(ACC, R)                                            \
        p.x = f2bf(ACC.x); p.y = f2bf(ACC.y);                             \
        p.z = f2bf(ACC.z); p.w = f2bf(ACC.w);                             \
        *reinterpret_cast<ushort4*>(sup + (size_t)(block_row + r0 + R) * D + cg * 4) = p;
    STORE_BF16(acc0, 0)
    STORE_BF16(acc1, 1)
    STORE_BF16(acc2, 2)
    STORE_BF16(acc3, 3)
    #undef STORE_BF16
}

__global__ __launch_bounds__(256) void scatter_edges(
    const int* __restrict__ row, const int* __restrict__ col,
    const float* __restrict__ ew, const unsigned short* __restrict__ sup,
    float* __restrict__ out)
{
    const int e = blockIdx.x * 8 + (threadIdx.x >> 5);
    if (e >= N_EDGES) return;
    const int lane = threadIdx.x & 31;

    const int r = row[e];
    const int c = col[e];
    const float w = ew[e];
    ushort4 s = reinterpret_cast<const ushort4*>(sup + (size_t)c * D)[lane];
    float* o = out + (size_t)r * D + lane * 4;
    atomicAdd(o + 0, w * bf2f(s.x));
    atomicAdd(o + 1, w * bf2f(s.y));
    atomicAdd(o + 2, w * bf2f(s.z));
    atomicAdd(o + 3, w * bf2f(s.w));
}

extern "C" void kernel_launch(void* const* d_in, const int* in_sizes, int n_in,
                              void* d_out, int out_size, void* d_ws, size_t ws_size,
                              hipStream_t stream)
{
    const float* x      = (const float*)d_in[0];   // [N_NODES, 128]
    const int*   row    = (const int*)d_in[1];     // [N_EDGES]
    const int*   col    = (const int*)d_in[2];     // [N_EDGES]
    const float* ew     = (const float*)d_in[3];   // [N_EDGES]
    const float* weight = (const float*)d_in[4];   // [128, 128]
    float* out = (float*)d_out;                    // [N_NODES, 128]

    char* ws = (char*)d_ws;
    const size_t off_sup     = 0;                                      // 25.6 MB
    const size_t off_head    = off_sup + (size_t)N_NODES * D * 2;      // 400 KB
    const size_t off_entries = off_head + (((size_t)N_NODES * 4 + 15) & ~(size_t)15);
    const size_t off_wt      = off_entries + (size_t)N_EDGES * 16;     // 32 KB
    const size_t required    = off_wt + (size_t)D * D * 2;

    unsigned short* sup = (unsigned short*)(ws + off_sup);

    if (ws_size >= required) {
        int*  head    = (int*)(ws + off_head);
        int4* entries = (int4*)(ws + off_entries);
        unsigned short* wt = (unsigned short*)(ws + off_wt);

        hipMemsetAsync(head, 0xFF, (size_t)N_NODES * 4, stream);       // head = -1
        w_prep<<<D * D / 256, 256, 0, stream>>>(weight, wt);

        // fused MFMA gemm + edge-list build
        gemm_build<<<GEMM_BLOCKS, 256, 0, stream>>>(
            x, wt, sup, row, col, ew, head, entries);

        // gather: writes every output row (no out memset needed)
        gather_list<<<N_NODES / 8, 256, 0, stream>>>(head, entries, sup, out);
    } else {
        gemm_xw<<<N_NODES / 32, 256, 0, stream>>>(x, weight, sup);
        hipMemsetAsync(d_out, 0, (size_t)N_NODES * D * sizeof(float), stream);
        scatter_edges<<<N_EDGES / 8, 256, 0, stream>>>(row, col, ew, sup, out);
    }
}